// Round 7
// baseline (153.312 us; speedup 1.0000x reference)
//
#include <hip/hip_runtime.h>
#include <hip/hip_fp16.h>

#define Nn 2048
#define Ff 64
#define Uu 64
#define NT 256
#define NCH 4          // K-chunks of 512

typedef _Float16 f16x4 __attribute__((ext_vector_type(4)));
typedef _Float16 f16x8 __attribute__((ext_vector_type(8)));
typedef float    f32x4 __attribute__((ext_vector_type(4)));

#define MFMA32(a,b,c) __builtin_amdgcn_mfma_f32_16x16x32_f16(a,b,c,0,0,0)
#define G1S 68         // padded g1 stride

// ---- X transpose: Xt[b][f][k] = (f16) X[b][k][f] ----
__global__ __launch_bounds__(256) void transposeX(const float* __restrict__ X,
                                                  _Float16* __restrict__ Xt) {
    __shared__ _Float16 tile[64][65];
    const int b = blockIdx.x, kt = blockIdx.y;
    #pragma unroll
    for (int i = 0; i < 16; ++i) {
        int e  = i * 256 + threadIdx.x;
        int kk = e >> 6, ff = e & 63;
        tile[ff][kk] = (_Float16)X[((size_t)b * Nn + kt * 64 + kk) * Ff + ff];
    }
    __syncthreads();
    #pragma unroll
    for (int i = 0; i < 16; ++i) {
        int e  = i * 256 + threadIdx.x;
        int ff = e >> 6, kk = e & 63;
        Xt[((size_t)b * Ff + ff) * Nn + kt * 64 + kk] = tile[ff][kk];
    }
}

// Stage a half-row: EVERY load is 64 lanes x 16B = 1KB fully contiguous.
#define ISSUE_HR(Vd,Vw0,Vw1,Vw2,Vg,Vk, C, HR) {               \
    const int _rr = (HR) >> 1;                                \
    const int _m  = ((C) << 9) + (((HR) & 1) << 8) + (lane << 2); \
    const size_t _o = (size_t)_rr * Nn + _m;                  \
    Vd  = *(const float4*)(dR + _o);                          \
    Vw0 = *(const float4*)(wR + 3 * _o);                      \
    Vw1 = *(const float4*)(wR + 3 * _o + 4);                  \
    Vw2 = *(const float4*)(wR + 3 * _o + 8);                  \
    Vg  = *(const float4*)(gR + _o);                          \
    Vk  = *(const float4*)(kR + _o);                          \
}

// exp(fusion)->f16, swizzled LDS write, register row-sum.
#define CONSUME_HR(Vd,Vw0,Vw1,Vw2,Vg,Vk, BUF, HR) {                           \
    const int _rr = (HR) >> 1;                                                \
    const int _tr = row0 + _rr;                                               \
    float _e0 = __expf(fminf(Vd.x*Vw0.x + Vg.x*Vw0.y + Vk.x*Vw0.z, 11.f));    \
    float _e1 = __expf(fminf(Vd.y*Vw0.w + Vg.y*Vw1.x + Vk.y*Vw1.y, 11.f));    \
    float _e2 = __expf(fminf(Vd.z*Vw1.z + Vg.z*Vw1.w + Vk.z*Vw2.x, 11.f));    \
    float _e3 = __expf(fminf(Vd.w*Vw2.y + Vg.w*Vw2.z + Vk.w*Vw2.w, 11.f));    \
    f16x4 _h = {(_Float16)_e0, (_Float16)_e1, (_Float16)_e2, (_Float16)_e3};  \
    rs[_rr] += (float)_h[0] + (float)_h[1] + (float)_h[2] + (float)_h[3];     \
    const int _ba = _tr*1024 + (((HR)&1) << 9) + (lane << 3);                 \
    *(f16x4*)((char*)(BUF) + (_ba ^ ((_tr & 7) << 4))) = _h;                  \
}

// full serial stage (prologue only)
#define STAGE_CHUNK(BUF, C) {                          \
    ISSUE_HR(Ad,Aw0,Aw1,Aw2,Ag,Ak, C, 0);              \
    ISSUE_HR(Bd,Bw0,Bw1,Bw2,Bg,Bk, C, 1);              \
    CONSUME_HR(Ad,Aw0,Aw1,Aw2,Ag,Ak, BUF, 0);          \
    ISSUE_HR(Ad,Aw0,Aw1,Aw2,Ag,Ak, C, 2);              \
    CONSUME_HR(Bd,Bw0,Bw1,Bw2,Bg,Bk, BUF, 1);          \
    ISSUE_HR(Bd,Bw0,Bw1,Bw2,Bg,Bk, C, 3);              \
    CONSUME_HR(Ad,Aw0,Aw1,Aw2,Ag,Ak, BUF, 2);          \
    ISSUE_HR(Ad,Aw0,Aw1,Aw2,Ag,Ak, C, 4);              \
    CONSUME_HR(Bd,Bw0,Bw1,Bw2,Bg,Bk, BUF, 3);          \
    ISSUE_HR(Bd,Bw0,Bw1,Bw2,Bg,Bk, C, 5);              \
    CONSUME_HR(Ad,Aw0,Aw1,Aw2,Ag,Ak, BUF, 4);          \
    ISSUE_HR(Ad,Aw0,Aw1,Aw2,Ag,Ak, C, 6);              \
    CONSUME_HR(Bd,Bw0,Bw1,Bw2,Bg,Bk, BUF, 5);          \
    ISSUE_HR(Bd,Bw0,Bw1,Bw2,Bg,Bk, C, 7);              \
    CONSUME_HR(Ad,Aw0,Aw1,Aw2,Ag,Ak, BUF, 6);          \
    CONSUME_HR(Bd,Bw0,Bw1,Bw2,Bg,Bk, BUF, 7);          \
}

__global__ __launch_bounds__(NT, 4) void fused_gcn(
    const _Float16* __restrict__ Xt,  // [B,F,N] f16
    const float* __restrict__ Dyn,    // [B,N,N]
    const float* __restrict__ Wf,     // [B,N,N,3]
    const float* __restrict__ Geo,    // [N,N]
    const float* __restrict__ KLm,    // [N,N]
    const float* __restrict__ Wd,     // [F,U]
    const float* __restrict__ bdv,    // [U]
    float* __restrict__ out)          // [B,N,U]
{
    __shared__ _Float16 Pb[2][16 * 512];   // double-buffered P tile
    __shared__ float wsumS[16];
    __shared__ float invS[16];

    const int t    = threadIdx.x;
    const int lane = t & 63;
    const int wid  = t >> 6;
    const int r    = lane & 15;
    const int kg   = lane >> 4;
    const int b    = blockIdx.x >> 7;
    const int n0   = (blockIdx.x & 127) << 4;
    const int row0 = wid << 2;

    const float* dR = Dyn + ((size_t)b * Nn + n0 + row0) * Nn;
    const float* wR = Wf  + ((size_t)b * Nn + n0 + row0) * (size_t)Nn * 3;
    const float* gR = Geo + (size_t)(n0 + row0) * Nn;
    const float* kR = KLm + (size_t)(n0 + row0) * Nn;
    const _Float16* XtB = Xt + (size_t)b * Ff * Nn;
    const _Float16* xw  = XtB + (size_t)(wid * 16 + r) * Nn + (kg << 3);

    f32x4 acc = {0.f, 0.f, 0.f, 0.f};
    float rs[4] = {0.f, 0.f, 0.f, 0.f};
    float4 Ad, Aw0, Aw1, Aw2, Ag, Ak;
    float4 Bd, Bw0, Bw1, Bw2, Bg, Bk;

    STAGE_CHUNK(&Pb[0][0], 0);      // prologue: stage chunk 0
    __syncthreads();

    #pragma unroll 1
    for (int c = 0; c < NCH - 1; ++c) {
        const char* bufc = (const char*)&Pb[c & 1][0];
        _Float16*   bufn = &Pb[(c + 1) & 1][0];
        const _Float16* xc = xw + (c << 9);

        // --- group-0 B-frags (L2), issued FIRST so MFMA waits never touch
        //     the stage queue (monotone in-order vmcnt) ---
        f16x8 bfA0 = *(const f16x8*)(xc);
        f16x8 bfA1 = *(const f16x8*)(xc + 32);
        f16x8 bfA2 = *(const f16x8*)(xc + 64);
        f16x8 bfA3 = *(const f16x8*)(xc + 96);
        f16x8 bfA4 = *(const f16x8*)(xc + 128);
        f16x8 bfA5 = *(const f16x8*)(xc + 160);
        f16x8 bfA6 = *(const f16x8*)(xc + 192);
        f16x8 bfA7 = *(const f16x8*)(xc + 224);
        // --- stage half-rows 0,1 of chunk c+1 (HBM): in flight through MFMA
        ISSUE_HR(Ad,Aw0,Aw1,Aw2,Ag,Ak, c + 1, 0);
        ISSUE_HR(Bd,Bw0,Bw1,Bw2,Bg,Bk, c + 1, 1);

        // --- MFMA steps 0..7 from LDS A-frags + bfA regs ---
        #pragma unroll
        for (int kk = 0; kk < 8; ++kk) {
            const int aa = r * 1024 + kk * 64 + kg * 16;
            f16x8 af = *(const f16x8*)(bufc + (aa ^ ((r & 7) << 4)));
            f16x8 bfv = (kk==0)?bfA0:(kk==1)?bfA1:(kk==2)?bfA2:(kk==3)?bfA3:
                        (kk==4)?bfA4:(kk==5)?bfA5:(kk==6)?bfA6:bfA7;
            acc = MFMA32(af, bfv, acc);
        }
        // --- group-1 B-frags; then MFMA 8..15 ---
        f16x8 bfB0 = *(const f16x8*)(xc + 256);
        f16x8 bfB1 = *(const f16x8*)(xc + 288);
        f16x8 bfB2 = *(const f16x8*)(xc + 320);
        f16x8 bfB3 = *(const f16x8*)(xc + 352);
        f16x8 bfB4 = *(const f16x8*)(xc + 384);
        f16x8 bfB5 = *(const f16x8*)(xc + 416);
        f16x8 bfB6 = *(const f16x8*)(xc + 448);
        f16x8 bfB7 = *(const f16x8*)(xc + 480);
        #pragma unroll
        for (int kk = 0; kk < 8; ++kk) {
            const int aa = r * 1024 + (kk + 8) * 64 + kg * 16;
            f16x8 af = *(const f16x8*)(bufc + (aa ^ ((r & 7) << 4)));
            f16x8 bfv = (kk==0)?bfB0:(kk==1)?bfB1:(kk==2)?bfB2:(kk==3)?bfB3:
                        (kk==4)?bfB4:(kk==5)?bfB5:(kk==6)?bfB6:bfB7;
            acc = MFMA32(af, bfv, acc);
        }

        // --- consume/issue depth-2 (identical to R6) ---
        CONSUME_HR(Ad,Aw0,Aw1,Aw2,Ag,Ak, bufn, 0);
        ISSUE_HR(Ad,Aw0,Aw1,Aw2,Ag,Ak, c + 1, 2);
        CONSUME_HR(Bd,Bw0,Bw1,Bw2,Bg,Bk, bufn, 1);
        ISSUE_HR(Bd,Bw0,Bw1,Bw2,Bg,Bk, c + 1, 3);
        CONSUME_HR(Ad,Aw0,Aw1,Aw2,Ag,Ak, bufn, 2);
        ISSUE_HR(Ad,Aw0,Aw1,Aw2,Ag,Ak, c + 1, 4);
        CONSUME_HR(Bd,Bw0,Bw1,Bw2,Bg,Bk, bufn, 3);
        ISSUE_HR(Bd,Bw0,Bw1,Bw2,Bg,Bk, c + 1, 5);
        CONSUME_HR(Ad,Aw0,Aw1,Aw2,Ag,Ak, bufn, 4);
        ISSUE_HR(Ad,Aw0,Aw1,Aw2,Ag,Ak, c + 1, 6);
        CONSUME_HR(Bd,Bw0,Bw1,Bw2,Bg,Bk, bufn, 5);
        ISSUE_HR(Bd,Bw0,Bw1,Bw2,Bg,Bk, c + 1, 7);
        CONSUME_HR(Ad,Aw0,Aw1,Aw2,Ag,Ak, bufn, 6);
        CONSUME_HR(Bd,Bw0,Bw1,Bw2,Bg,Bk, bufn, 7);
        __syncthreads();
    }

    // --- last chunk: MFMA only ---
    {
        const char* bufc = (const char*)&Pb[(NCH - 1) & 1][0];
        const _Float16* xc = xw + ((NCH - 1) << 9);
        #pragma unroll
        for (int kk = 0; kk < 16; ++kk) {
            const int aa = r * 1024 + kk * 64 + kg * 16;
            f16x8 af = *(const f16x8*)(bufc + (aa ^ ((r & 7) << 4)));
            f16x8 bf = *(const f16x8*)(xc + kk * 32);
            acc = MFMA32(af, bf, acc);
        }
    }

    // ---- epilogue: row sums -> inv, normalize into g1, Dense + tanh ----
    #pragma unroll
    for (int i = 0; i < 4; ++i) {
        float v = rs[i];
        v += __shfl_xor(v, 1, 64);  v += __shfl_xor(v, 2, 64);
        v += __shfl_xor(v, 4, 64);  v += __shfl_xor(v, 8, 64);
        v += __shfl_xor(v, 16, 64); v += __shfl_xor(v, 32, 64);
        rs[i] = v;
    }
    if (lane == 0) {
        wsumS[row0 + 0] = rs[0]; wsumS[row0 + 1] = rs[1];
        wsumS[row0 + 2] = rs[2]; wsumS[row0 + 3] = rs[3];
    }
    __syncthreads();
    if (t < 16) invS[t] = 1.0f / wsumS[t];
    __syncthreads();

    float* g1 = (float*)&Pb[0][0];
    #pragma unroll
    for (int i = 0; i < 4; ++i) {
        const int ro = (kg << 2) + i;
        g1[ro * G1S + (wid << 4) + r] = acc[i] * invS[ro];
    }
    __syncthreads();

    const float* g1r = g1 + row0 * G1S;
    float o0 = bdv[lane], o1 = o0, o2 = o0, o3 = o0;
    #pragma unroll 4
    for (int f = 0; f < Ff; ++f) {
        float wdv = Wd[f * Uu + lane];
        o0 += g1r[f]           * wdv;
        o1 += g1r[G1S + f]     * wdv;
        o2 += g1r[2 * G1S + f] * wdv;
        o3 += g1r[3 * G1S + f] * wdv;
    }
    float oo[4] = {o0, o1, o2, o3};
    #pragma unroll
    for (int i = 0; i < 4; ++i) {
        float x  = fminf(fmaxf(oo[i], -15.f), 15.f);
        float ex = __expf(2.f * x);
        out[((size_t)b * Nn + n0 + row0 + i) * Uu + lane] = (ex - 1.f) / (ex + 1.f);
    }
}

extern "C" void kernel_launch(void* const* d_in, const int* in_sizes, int n_in,
                              void* d_out, int out_size, void* d_ws, size_t ws_size,
                              hipStream_t stream) {
    const float* X   = (const float*)d_in[0];
    const float* Dyn = (const float*)d_in[1];
    const float* Wf  = (const float*)d_in[2];
    const float* Geo = (const float*)d_in[3];
    const float* KLm = (const float*)d_in[4];
    const float* Wd  = (const float*)d_in[5];
    const float* bdv = (const float*)d_in[6];
    float* out = (float*)d_out;

    _Float16* Xt = (_Float16*)d_ws;   // 2 MB, ws_size verified >= this in R4-R6
    transposeX<<<dim3(8, Nn / 64), dim3(256), 0, stream>>>(X, Xt);
    fused_gcn<<<dim3(8 * (Nn / 16)), dim3(NT), 0, stream>>>(
        Xt, Dyn, Wf, Geo, KLm, Wd, bdv, out);
}

// Round 8
// 129.514 us; speedup vs baseline: 1.1838x; 1.1838x over previous
//
#include <hip/hip_runtime.h>
#include <hip/hip_fp16.h>

#define Nn 2048
#define Ff 64
#define Uu 64
#define NT 256
#define NCH 4          // K-chunks of 512

typedef _Float16 f16x4 __attribute__((ext_vector_type(4)));
typedef _Float16 f16x8 __attribute__((ext_vector_type(8)));
typedef float    f32x4 __attribute__((ext_vector_type(4)));

#define MFMA32(a,b,c) __builtin_amdgcn_mfma_f32_16x16x32_f16(a,b,c,0,0,0)
#define G1S 68         // padded g1 stride

// ---- X transpose: Xt[b][f][k] = (f16) X[b][k][f] ----
__global__ __launch_bounds__(256) void transposeX(const float* __restrict__ X,
                                                  _Float16* __restrict__ Xt) {
    __shared__ _Float16 tile[64][65];
    const int b = blockIdx.x, kt = blockIdx.y;
    #pragma unroll
    for (int i = 0; i < 16; ++i) {
        int e  = i * 256 + threadIdx.x;
        int kk = e >> 6, ff = e & 63;
        tile[ff][kk] = (_Float16)X[((size_t)b * Nn + kt * 64 + kk) * Ff + ff];
    }
    __syncthreads();
    #pragma unroll
    for (int i = 0; i < 16; ++i) {
        int e  = i * 256 + threadIdx.x;
        int ff = e >> 6, kk = e & 63;
        Xt[((size_t)b * Ff + ff) * Nn + kt * 64 + kk] = tile[ff][kk];
    }
}

// Stage a half-row: EVERY load is 64 lanes x 16B = 1KB fully contiguous.
#define ISSUE_HR(Vd,Vw0,Vw1,Vw2,Vg,Vk, C, HR) {               \
    const int _rr = (HR) >> 1;                                \
    const int _m  = ((C) << 9) + (((HR) & 1) << 8) + (lane << 2); \
    const size_t _o = (size_t)_rr * Nn + _m;                  \
    Vd  = *(const float4*)(dR + _o);                          \
    Vw0 = *(const float4*)(wR + 3 * _o);                      \
    Vw1 = *(const float4*)(wR + 3 * _o + 4);                  \
    Vw2 = *(const float4*)(wR + 3 * _o + 8);                  \
    Vg  = *(const float4*)(gR + _o);                          \
    Vk  = *(const float4*)(kR + _o);                          \
}

// exp(fusion)->f16, swizzled LDS write, register row-sum.
#define CONSUME_HR(Vd,Vw0,Vw1,Vw2,Vg,Vk, BUF, HR) {                           \
    const int _rr = (HR) >> 1;                                                \
    const int _tr = row0 + _rr;                                               \
    float _e0 = __expf(fminf(Vd.x*Vw0.x + Vg.x*Vw0.y + Vk.x*Vw0.z, 11.f));    \
    float _e1 = __expf(fminf(Vd.y*Vw0.w + Vg.y*Vw1.x + Vk.y*Vw1.y, 11.f));    \
    float _e2 = __expf(fminf(Vd.z*Vw1.z + Vg.z*Vw1.w + Vk.z*Vw2.x, 11.f));    \
    float _e3 = __expf(fminf(Vd.w*Vw2.y + Vg.w*Vw2.z + Vk.w*Vw2.w, 11.f));    \
    f16x4 _h = {(_Float16)_e0, (_Float16)_e1, (_Float16)_e2, (_Float16)_e3};  \
    rs[_rr] += (float)_h[0] + (float)_h[1] + (float)_h[2] + (float)_h[3];     \
    const int _ba = _tr*1024 + (((HR)&1) << 9) + (lane << 3);                 \
    *(f16x4*)((char*)(BUF) + (_ba ^ ((_tr & 7) << 4))) = _h;                  \
}

// depth-2 pipelined stage of one chunk (R6-verified)
#define STAGE_CHUNK(BUF, C) {                          \
    ISSUE_HR(Ad,Aw0,Aw1,Aw2,Ag,Ak, C, 0);              \
    ISSUE_HR(Bd,Bw0,Bw1,Bw2,Bg,Bk, C, 1);              \
    CONSUME_HR(Ad,Aw0,Aw1,Aw2,Ag,Ak, BUF, 0);          \
    ISSUE_HR(Ad,Aw0,Aw1,Aw2,Ag,Ak, C, 2);              \
    CONSUME_HR(Bd,Bw0,Bw1,Bw2,Bg,Bk, BUF, 1);          \
    ISSUE_HR(Bd,Bw0,Bw1,Bw2,Bg,Bk, C, 3);              \
    CONSUME_HR(Ad,Aw0,Aw1,Aw2,Ag,Ak, BUF, 2);          \
    ISSUE_HR(Ad,Aw0,Aw1,Aw2,Ag,Ak, C, 4);              \
    CONSUME_HR(Bd,Bw0,Bw1,Bw2,Bg,Bk, BUF, 3);          \
    ISSUE_HR(Bd,Bw0,Bw1,Bw2,Bg,Bk, C, 5);              \
    CONSUME_HR(Ad,Aw0,Aw1,Aw2,Ag,Ak, BUF, 4);          \
    ISSUE_HR(Ad,Aw0,Aw1,Aw2,Ag,Ak, C, 6);              \
    CONSUME_HR(Bd,Bw0,Bw1,Bw2,Bg,Bk, BUF, 5);          \
    ISSUE_HR(Bd,Bw0,Bw1,Bw2,Bg,Bk, C, 7);              \
    CONSUME_HR(Ad,Aw0,Aw1,Aw2,Ag,Ak, BUF, 6);          \
    CONSUME_HR(Bd,Bw0,Bw1,Bw2,Bg,Bk, BUF, 7);          \
}

// MFMA phase for one chunk: B-frags prefetched in 2 groups of 8 (32 VGPRs,
// live only inside this phase — stage regs are dead here, so peak pressure
// stays at R6 level). No stage loads are outstanding during this phase, so
// group-A waits don't drain anything (in-order vmcnt safe).
#define MFMA_PHASE(BUFC, XC) {                                                \
    f16x8 p0 = *(const f16x8*)((XC));                                         \
    f16x8 p1 = *(const f16x8*)((XC) + 32);                                    \
    f16x8 p2 = *(const f16x8*)((XC) + 64);                                    \
    f16x8 p3 = *(const f16x8*)((XC) + 96);                                    \
    f16x8 p4 = *(const f16x8*)((XC) + 128);                                   \
    f16x8 p5 = *(const f16x8*)((XC) + 160);                                   \
    f16x8 p6 = *(const f16x8*)((XC) + 192);                                   \
    f16x8 p7 = *(const f16x8*)((XC) + 224);                                   \
    _Pragma("unroll")                                                         \
    for (int kk = 0; kk < 8; ++kk) {                                          \
        const int aa = r * 1024 + kk * 64 + kg * 16;                          \
        f16x8 af = *(const f16x8*)((BUFC) + (aa ^ ((r & 7) << 4)));           \
        f16x8 bv = (kk==0)?p0:(kk==1)?p1:(kk==2)?p2:(kk==3)?p3:               \
                   (kk==4)?p4:(kk==5)?p5:(kk==6)?p6:p7;                       \
        acc = MFMA32(af, bv, acc);                                            \
    }                                                                         \
    p0 = *(const f16x8*)((XC) + 256);                                         \
    p1 = *(const f16x8*)((XC) + 288);                                         \
    p2 = *(const f16x8*)((XC) + 320);                                         \
    p3 = *(const f16x8*)((XC) + 352);                                         \
    p4 = *(const f16x8*)((XC) + 384);                                         \
    p5 = *(const f16x8*)((XC) + 416);                                         \
    p6 = *(const f16x8*)((XC) + 448);                                         \
    p7 = *(const f16x8*)((XC) + 480);                                         \
    _Pragma("unroll")                                                         \
    for (int kk = 0; kk < 8; ++kk) {                                          \
        const int aa = r * 1024 + (kk + 8) * 64 + kg * 16;                    \
        f16x8 af = *(const f16x8*)((BUFC) + (aa ^ ((r & 7) << 4)));           \
        f16x8 bv = (kk==0)?p0:(kk==1)?p1:(kk==2)?p2:(kk==3)?p3:               \
                   (kk==4)?p4:(kk==5)?p5:(kk==6)?p6:p7;                       \
        acc = MFMA32(af, bv, acc);                                            \
    }                                                                         \
}

__global__ __launch_bounds__(NT, 4) void fused_gcn(
    const _Float16* __restrict__ Xt,  // [B,F,N] f16
    const float* __restrict__ Dyn,    // [B,N,N]
    const float* __restrict__ Wf,     // [B,N,N,3]
    const float* __restrict__ Geo,    // [N,N]
    const float* __restrict__ KLm,    // [N,N]
    const float* __restrict__ Wd,     // [F,U]
    const float* __restrict__ bdv,    // [U]
    float* __restrict__ out)          // [B,N,U]
{
    __shared__ _Float16 Pb[2][16 * 512];   // double-buffered P tile
    __shared__ float wsumS[16];
    __shared__ float invS[16];

    const int t    = threadIdx.x;
    const int lane = t & 63;
    const int wid  = t >> 6;
    const int r    = lane & 15;
    const int kg   = lane >> 4;
    const int b    = blockIdx.x >> 7;
    const int n0   = (blockIdx.x & 127) << 4;
    const int row0 = wid << 2;

    const float* dR = Dyn + ((size_t)b * Nn + n0 + row0) * Nn;
    const float* wR = Wf  + ((size_t)b * Nn + n0 + row0) * (size_t)Nn * 3;
    const float* gR = Geo + (size_t)(n0 + row0) * Nn;
    const float* kR = KLm + (size_t)(n0 + row0) * Nn;
    const _Float16* XtB = Xt + (size_t)b * Ff * Nn;
    const _Float16* xw  = XtB + (size_t)(wid * 16 + r) * Nn + (kg << 3);

    f32x4 acc = {0.f, 0.f, 0.f, 0.f};
    float rs[4] = {0.f, 0.f, 0.f, 0.f};
    float4 Ad, Aw0, Aw1, Aw2, Ag, Ak;
    float4 Bd, Bw0, Bw1, Bw2, Bg, Bk;

    STAGE_CHUNK(&Pb[0][0], 0);      // prologue: stage chunk 0
    __syncthreads();

    #pragma unroll 1
    for (int c = 0; c < NCH; ++c) {
        const char* bufc = (const char*)&Pb[c & 1][0];
        MFMA_PHASE(bufc, xw + (c << 9));
        if (c + 1 < NCH) {
            _Float16* bufn = &Pb[(c + 1) & 1][0];
            STAGE_CHUNK(bufn, c + 1);
        }
        __syncthreads();
    }

    // ---- epilogue: row sums -> inv, normalize into g1, Dense + tanh ----
    #pragma unroll
    for (int i = 0; i < 4; ++i) {
        float v = rs[i];
        v += __shfl_xor(v, 1, 64);  v += __shfl_xor(v, 2, 64);
        v += __shfl_xor(v, 4, 64);  v += __shfl_xor(v, 8, 64);
        v += __shfl_xor(v, 16, 64); v += __shfl_xor(v, 32, 64);
        rs[i] = v;
    }
    if (lane == 0) {
        wsumS[row0 + 0] = rs[0]; wsumS[row0 + 1] = rs[1];
        wsumS[row0 + 2] = rs[2]; wsumS[row0 + 3] = rs[3];
    }
    __syncthreads();
    if (t < 16) invS[t] = 1.0f / wsumS[t];
    __syncthreads();

    float* g1 = (float*)&Pb[0][0];
    #pragma unroll
    for (int i = 0; i < 4; ++i) {
        const int ro = (kg << 2) + i;
        g1[ro * G1S + (wid << 4) + r] = acc[i] * invS[ro];
    }
    __syncthreads();

    const float* g1r = g1 + row0 * G1S;
    float o0 = bdv[lane], o1 = o0, o2 = o0, o3 = o0;
    #pragma unroll 4
    for (int f = 0; f < Ff; ++f) {
        float wdv = Wd[f * Uu + lane];
        o0 += g1r[f]           * wdv;
        o1 += g1r[G1S + f]     * wdv;
        o2 += g1r[2 * G1S + f] * wdv;
        o3 += g1r[3 * G1S + f] * wdv;
    }
    float oo[4] = {o0, o1, o2, o3};
    #pragma unroll
    for (int i = 0; i < 4; ++i) {
        float x  = fminf(fmaxf(oo[i], -15.f), 15.f);
        float ex = __expf(2.f * x);
        out[((size_t)b * Nn + n0 + row0 + i) * Uu + lane] = (ex - 1.f) / (ex + 1.f);
    }
}

extern "C" void kernel_launch(void* const* d_in, const int* in_sizes, int n_in,
                              void* d_out, int out_size, void* d_ws, size_t ws_size,
                              hipStream_t stream) {
    const float* X   = (const float*)d_in[0];
    const float* Dyn = (const float*)d_in[1];
    const float* Wf  = (const float*)d_in[2];
    const float* Geo = (const float*)d_in[3];
    const float* KLm = (const float*)d_in[4];
    const float* Wd  = (const float*)d_in[5];
    const float* bdv = (const float*)d_in[6];
    float* out = (float*)d_out;

    _Float16* Xt = (_Float16*)d_ws;   // 2 MB scratch
    transposeX<<<dim3(8, Nn / 64), dim3(256), 0, stream>>>(X, Xt);
    fused_gcn<<<dim3(8 * (Nn / 16)), dim3(NT), 0, stream>>>(
        Xt, Dyn, Wf, Geo, KLm, Wd, bdv, out);
}